// Round 1
// baseline (3356.784 us; speedup 1.0000x reference)
//
#include <hip/hip_runtime.h>
#include <hip/hip_bf16.h>

#define N_NODES 100000
#define N_EDGES 3200000
#define IN_DIM 256
#define HID 128
#define BN_EPS 1e-5f

// ---------------- degree / dinv / sigmoid ----------------

__global__ void k_deg(const int* __restrict__ col, unsigned* __restrict__ cnt) {
    int i = blockIdx.x * blockDim.x + threadIdx.x;
    if (i < N_EDGES) atomicAdd(&cnt[col[i]], 1u);
}

__global__ void k_dinv(const unsigned* __restrict__ cnt, float* __restrict__ dinv) {
    int i = blockIdx.x * blockDim.x + threadIdx.x;
    if (i < N_NODES) dinv[i] = rsqrtf((float)(cnt[i] + 1u));  // +1 self-loop
}

__global__ void k_sig(const float* __restrict__ fi, float* __restrict__ sig) {
    int i = threadIdx.x;
    if (i < IN_DIM) sig[i] = 1.0f / (1.0f + expf(-fi[i]));
}

// ---------------- GEMM1: hs[n][j] = dinv[n] * sum_k x[n][k]*sig[k]*W1[k][j] ----------------
// 64x128 output tile per block, BK=16, 256 threads, 8x4 per thread.

__global__ __launch_bounds__(256) void k_gemm1(const float* __restrict__ x,
                                               const float* __restrict__ W1,
                                               const float* __restrict__ sig,
                                               const float* __restrict__ dinv,
                                               float* __restrict__ hs) {
    __shared__ float xT[16][64];    // [k][m] transposed x tile
    __shared__ float Wl[16][128];   // [k][n]
    const int mbase = blockIdx.x * 64;
    const int t = threadIdx.x;
    const int tm = t >> 5;          // 0..7  (row group of 8)
    const int tn = t & 31;          // 0..31 (col group of 4)
    float acc[8][4] = {{0.f}};

    for (int k0 = 0; k0 < IN_DIM; k0 += 16) {
        // load x tile: 64 rows x 16 k; thread -> one float4
        {
            int r = t >> 2;             // 0..63
            int kk = (t & 3) * 4;       // 0,4,8,12
            int row = mbase + r;
            float4 v = make_float4(0.f, 0.f, 0.f, 0.f);
            if (row < N_NODES) v = *(const float4*)&x[row * IN_DIM + k0 + kk];
            xT[kk + 0][r] = v.x; xT[kk + 1][r] = v.y;
            xT[kk + 2][r] = v.z; xT[kk + 3][r] = v.w;
        }
        // load W tile: 16 k x 128 n, fold sigmoid(fi[k])
        {
#pragma unroll
            for (int i = 0; i < 2; ++i) {
                int idx = t + i * 256;          // float4 index, 0..511
                int k = idx >> 5;               // 0..15
                int n4 = (idx & 31) * 4;
                float4 w = *(const float4*)&W1[(k0 + k) * HID + n4];
                float s = sig[k0 + k];
                Wl[k][n4 + 0] = w.x * s; Wl[k][n4 + 1] = w.y * s;
                Wl[k][n4 + 2] = w.z * s; Wl[k][n4 + 3] = w.w * s;
            }
        }
        __syncthreads();
#pragma unroll
        for (int k = 0; k < 16; ++k) {
            float xv[8], wv[4];
            *(float4*)&xv[0] = *(const float4*)&xT[k][tm * 8];
            *(float4*)&xv[4] = *(const float4*)&xT[k][tm * 8 + 4];
            *(float4*)&wv[0] = *(const float4*)&Wl[k][tn * 4];
#pragma unroll
            for (int i = 0; i < 8; ++i)
#pragma unroll
                for (int j = 0; j < 4; ++j)
                    acc[i][j] += xv[i] * wv[j];
        }
        __syncthreads();
    }
#pragma unroll
    for (int i = 0; i < 8; ++i) {
        int row = mbase + tm * 8 + i;
        if (row < N_NODES) {
            float d = dinv[row];
            float4 v = make_float4(acc[i][0] * d, acc[i][1] * d, acc[i][2] * d, acc[i][3] * d);
            *(float4*)&hs[row * HID + tn * 4] = v;
        }
    }
}

// ---------------- aggregation 1: S1[c][:] += hs[r][:] (wave per edge) ----------------

__global__ __launch_bounds__(256) void k_agg1(const int* __restrict__ row,
                                              const int* __restrict__ col,
                                              const float* __restrict__ hs,
                                              float* __restrict__ S1) {
    int wid = (blockIdx.x * blockDim.x + threadIdx.x) >> 6;
    int lane = threadIdx.x & 63;
    int nw = (gridDim.x * blockDim.x) >> 6;
    for (int e = wid; e < N_EDGES; e += nw) {
        int r = row[e], c = col[e];
        float2 v = *(const float2*)&hs[r * HID + lane * 2];
        atomicAdd(&S1[c * HID + lane * 2 + 0], v.x);
        atomicAdd(&S1[c * HID + lane * 2 + 1], v.y);
    }
}

// ---------------- fix-up 1 (+ self-loop + b1) fused with BN partial stats ----------------

__global__ __launch_bounds__(256) void k_fix1(const float* __restrict__ hs,
                                              const float* __restrict__ dinv,
                                              const float* __restrict__ b1,
                                              float* __restrict__ S1,
                                              float* __restrict__ stats) {
    __shared__ float red[256];
    int t = threadIdx.x;
    int j = t & 127;
    float b = b1[j];
    float sum = 0.f, sumsq = 0.f;
    int stride = (gridDim.x * blockDim.x) >> 7;
    for (int c = (blockIdx.x * blockDim.x + t) >> 7; c < N_NODES; c += stride) {
        int idx = c * HID + j;
        float d = dinv[c];
        float v = d * (S1[idx] + hs[idx]) + b;   // dinv[c]*(sum_neighbors + self-loop hs[c]) + b1
        S1[idx] = v;
        sum += v; sumsq += v * v;
    }
    red[t] = sum;
    __syncthreads();
    float s2 = (t < 128) ? (red[t] + red[t + 128]) : 0.f;
    __syncthreads();
    red[t] = sumsq;
    __syncthreads();
    if (t < 128) {
        float q2 = red[t] + red[t + 128];
        atomicAdd(&stats[j], s2);
        atomicAdd(&stats[128 + j], q2);
    }
}

// ---------------- BN finalize: scale/shift per channel ----------------

__global__ void k_bnfin(const float* __restrict__ stats,
                        const float* __restrict__ gamma,
                        const float* __restrict__ beta,
                        float* __restrict__ bnp) {
    int j = threadIdx.x;
    if (j < HID) {
        float mu = stats[j] * (1.0f / N_NODES);
        float var = stats[128 + j] * (1.0f / N_NODES) - mu * mu;
        float rstd = rsqrtf(var + BN_EPS);
        float sc = rstd * gamma[j];
        bnp[j] = sc;
        bnp[128 + j] = beta[j] - mu * sc;
    }
}

// ---------------- GEMM2 fused: gs[n][0:2] = dinv[n] * relu(bn(S1[n])) @ W2 ----------------
// one wave per node; lane handles channels 2*lane, 2*lane+1

__global__ __launch_bounds__(256) void k_gemm2(const float* __restrict__ S1,
                                               const float* __restrict__ bnp,
                                               const float* __restrict__ W2,
                                               const float* __restrict__ dinv,
                                               float* __restrict__ gs) {
    int wid = (blockIdx.x * blockDim.x + threadIdx.x) >> 6;
    int lane = threadIdx.x & 63;
    int nw = (gridDim.x * blockDim.x) >> 6;
    int k0 = lane * 2;
    float2 sc = *(const float2*)&bnp[k0];
    float2 sh = *(const float2*)&bnp[128 + k0];
    float4 w = *(const float4*)&W2[k0 * 2];  // W2[k0][0..1], W2[k0+1][0..1]
    for (int n = wid; n < N_NODES; n += nw) {
        float2 h = *(const float2*)&S1[n * HID + k0];
        float v0 = fmaxf(h.x * sc.x + sh.x, 0.f);
        float v1 = fmaxf(h.y * sc.y + sh.y, 0.f);
        float a0 = v0 * w.x + v1 * w.z;
        float a1 = v0 * w.y + v1 * w.w;
#pragma unroll
        for (int off = 32; off; off >>= 1) {
            a0 += __shfl_down(a0, off);
            a1 += __shfl_down(a1, off);
        }
        if (lane == 0) {
            float d = dinv[n];
            float2 o = make_float2(a0 * d, a1 * d);
            *(float2*)&gs[n * 2] = o;
        }
    }
}

// ---------------- aggregation 2: S2[c][0:2] += gs[r][0:2] (thread per edge) ----------------

__global__ __launch_bounds__(256) void k_agg2(const int* __restrict__ row,
                                              const int* __restrict__ col,
                                              const float* __restrict__ gs,
                                              float* __restrict__ S2) {
    int i = blockIdx.x * blockDim.x + threadIdx.x;
    int nt = gridDim.x * blockDim.x;
    for (int e = i; e < N_EDGES; e += nt) {
        int r = row[e], c = col[e];
        float2 v = *(const float2*)&gs[r * 2];
        atomicAdd(&S2[c * 2 + 0], v.x);
        atomicAdd(&S2[c * 2 + 1], v.y);
    }
}

// ---------------- fix-up 2: out[c] = dinv[c]*(S2[c] + gs[c]) + b2 ----------------

__global__ void k_fix2(const float* __restrict__ S2,
                       const float* __restrict__ gs,
                       const float* __restrict__ dinv,
                       const float* __restrict__ b2,
                       float* __restrict__ out) {
    int c = blockIdx.x * blockDim.x + threadIdx.x;
    if (c < N_NODES) {
        float d = dinv[c];
        float2 s = *(const float2*)&S2[c * 2];
        float2 g = *(const float2*)&gs[c * 2];
        float2 o = make_float2(d * (s.x + g.x) + b2[0], d * (s.y + g.y) + b2[1]);
        *(float2*)&out[c * 2] = o;
    }
}

// ---------------- launch ----------------

extern "C" void kernel_launch(void* const* d_in, const int* in_sizes, int n_in,
                              void* d_out, int out_size, void* d_ws, size_t ws_size,
                              hipStream_t stream) {
    const float* x     = (const float*)d_in[0];
    const int*   edge  = (const int*)d_in[1];      // [2, E]: row = edge[0..E), col = edge[E..2E)
    const float* fi    = (const float*)d_in[2];
    const float* W1    = (const float*)d_in[3];
    const float* b1    = (const float*)d_in[4];
    const float* W2    = (const float*)d_in[5];
    const float* b2    = (const float*)d_in[6];
    const float* gamma = (const float*)d_in[7];
    const float* beta  = (const float*)d_in[8];
    float* out = (float*)d_out;

    const int* erow = edge;
    const int* ecol = edge + N_EDGES;

    // workspace layout (256B aligned)
    char* ws = (char*)d_ws;
    size_t off = 0;
    auto alloc = [&](size_t bytes) { size_t r = off; off = (off + bytes + 255) & ~(size_t)255; return r; };
    float*    hs    = (float*)(ws + alloc(sizeof(float) * N_NODES * HID));   // 51.2 MB
    float*    S1    = (float*)(ws + alloc(sizeof(float) * N_NODES * HID));   // 51.2 MB
    float*    gs    = (float*)(ws + alloc(sizeof(float) * N_NODES * 2));     // 0.8 MB
    float*    S2    = (float*)(ws + alloc(sizeof(float) * N_NODES * 2));     // 0.8 MB
    unsigned* cnt   = (unsigned*)(ws + alloc(sizeof(unsigned) * N_NODES));   // 0.4 MB
    float*    dinv  = (float*)(ws + alloc(sizeof(float) * N_NODES));         // 0.4 MB
    float*    sig   = (float*)(ws + alloc(sizeof(float) * IN_DIM));
    float*    stats = (float*)(ws + alloc(sizeof(float) * 2 * HID));
    float*    bnp   = (float*)(ws + alloc(sizeof(float) * 2 * HID));
    (void)ws_size; (void)in_sizes; (void)n_in; (void)out_size;

    // zero the accumulators (ws is poisoned 0xAA before every timed call)
    hipMemsetAsync(cnt, 0, sizeof(unsigned) * N_NODES, stream);
    hipMemsetAsync(S1, 0, sizeof(float) * N_NODES * HID, stream);
    hipMemsetAsync(S2, 0, sizeof(float) * N_NODES * 2, stream);
    hipMemsetAsync(stats, 0, sizeof(float) * 2 * HID, stream);

    k_deg<<<(N_EDGES + 255) / 256, 256, 0, stream>>>(ecol, cnt);
    k_dinv<<<(N_NODES + 255) / 256, 256, 0, stream>>>(cnt, dinv);
    k_sig<<<1, 256, 0, stream>>>(fi, sig);

    k_gemm1<<<(N_NODES + 63) / 64, 256, 0, stream>>>(x, W1, sig, dinv, hs);
    k_agg1<<<2048, 256, 0, stream>>>(erow, ecol, hs, S1);
    k_fix1<<<1024, 256, 0, stream>>>(hs, dinv, b1, S1, stats);
    k_bnfin<<<1, 128, 0, stream>>>(stats, gamma, beta, bnp);
    k_gemm2<<<2048, 256, 0, stream>>>(S1, bnp, W2, dinv, gs);
    k_agg2<<<2048, 256, 0, stream>>>(erow, ecol, gs, S2);
    k_fix2<<<(N_NODES + 255) / 256, 256, 0, stream>>>(S2, gs, dinv, b2, out);
}

// Round 2
// 895.605 us; speedup vs baseline: 3.7481x; 3.7481x over previous
//
#include <hip/hip_runtime.h>
#include <hip/hip_bf16.h>

#define N_NODES 100000
#define N_EDGES 3200000
#define IN_DIM 256
#define HID 128
#define BN_EPS 1e-5f
#define SCAN_B 1024
#define NB1 ((N_NODES + SCAN_B - 1) / SCAN_B)   // 98

// ---------------- degree / dinv / sigmoid ----------------

__global__ void k_deg(const int* __restrict__ col, unsigned* __restrict__ cnt) {
    int i = blockIdx.x * blockDim.x + threadIdx.x;
    if (i < N_EDGES) atomicAdd(&cnt[col[i]], 1u);
}

__global__ void k_dinv(const unsigned* __restrict__ cnt, float* __restrict__ dinv) {
    int i = blockIdx.x * blockDim.x + threadIdx.x;
    if (i < N_NODES) dinv[i] = rsqrtf((float)(cnt[i] + 1u));  // +1 self-loop
}

__global__ void k_sig(const float* __restrict__ fi, float* __restrict__ sig) {
    int i = threadIdx.x;
    if (i < IN_DIM) sig[i] = 1.0f / (1.0f + expf(-fi[i]));
}

// ---------------- exclusive prefix scan of cnt -> rowptr ----------------

__global__ __launch_bounds__(SCAN_B) void k_scan_part(const unsigned* __restrict__ cnt,
                                                      unsigned* __restrict__ rowptr,
                                                      unsigned* __restrict__ blocksum) {
    __shared__ unsigned s[SCAN_B];
    int t = threadIdx.x;
    int i = blockIdx.x * SCAN_B + t;
    unsigned v = (i < N_NODES) ? cnt[i] : 0u;
    s[t] = v;
    __syncthreads();
#pragma unroll
    for (int off = 1; off < SCAN_B; off <<= 1) {
        unsigned u = (t >= off) ? s[t - off] : 0u;
        __syncthreads();
        s[t] += u;
        __syncthreads();
    }
    if (i < N_NODES) rowptr[i] = s[t] - v;       // exclusive within block
    if (t == SCAN_B - 1) blocksum[blockIdx.x] = s[t];
}

__global__ __launch_bounds__(128) void k_scan_mid(const unsigned* __restrict__ blocksum,
                                                  unsigned* __restrict__ blockoff) {
    __shared__ unsigned s[128];
    int t = threadIdx.x;
    unsigned v = (t < NB1) ? blocksum[t] : 0u;
    s[t] = v;
    __syncthreads();
#pragma unroll
    for (int off = 1; off < 128; off <<= 1) {
        unsigned u = (t >= off) ? s[t - off] : 0u;
        __syncthreads();
        s[t] += u;
        __syncthreads();
    }
    if (t < NB1) blockoff[t] = s[t] - v;         // exclusive
}

__global__ void k_scan_add(unsigned* __restrict__ rowptr, const unsigned* __restrict__ blockoff) {
    int i = blockIdx.x * blockDim.x + threadIdx.x;
    if (i < N_NODES) rowptr[i] += blockoff[i >> 10];
    if (i == 0) rowptr[N_NODES] = N_EDGES;
}

// ---------------- bucket: esrc sorted by destination ----------------

__global__ void k_bucket(const int* __restrict__ row, const int* __restrict__ col,
                         const unsigned* __restrict__ rowptr, unsigned* __restrict__ fill,
                         int* __restrict__ esrc) {
    int e = blockIdx.x * blockDim.x + threadIdx.x;
    if (e < N_EDGES) {
        int c = col[e];
        unsigned p = rowptr[c] + atomicAdd(&fill[c], 1u);
        esrc[p] = row[e];
    }
}

// ---------------- GEMM1: hs[n][j] = dinv[n] * sum_k x[n][k]*sig[k]*W1[k][j] ----------------
// 64x128 output tile per block, BK=16, 256 threads, 8x4 per thread.

__global__ __launch_bounds__(256) void k_gemm1(const float* __restrict__ x,
                                               const float* __restrict__ W1,
                                               const float* __restrict__ sig,
                                               const float* __restrict__ dinv,
                                               float* __restrict__ hs) {
    __shared__ float xT[16][64];    // [k][m] transposed x tile
    __shared__ float Wl[16][128];   // [k][n]
    const int mbase = blockIdx.x * 64;
    const int t = threadIdx.x;
    const int tm = t >> 5;          // 0..7  (row group of 8)
    const int tn = t & 31;          // 0..31 (col group of 4)
    float acc[8][4] = {{0.f}};

    for (int k0 = 0; k0 < IN_DIM; k0 += 16) {
        {
            int r = t >> 2;             // 0..63
            int kk = (t & 3) * 4;       // 0,4,8,12
            int row = mbase + r;
            float4 v = make_float4(0.f, 0.f, 0.f, 0.f);
            if (row < N_NODES) v = *(const float4*)&x[row * IN_DIM + k0 + kk];
            xT[kk + 0][r] = v.x; xT[kk + 1][r] = v.y;
            xT[kk + 2][r] = v.z; xT[kk + 3][r] = v.w;
        }
        {
#pragma unroll
            for (int i = 0; i < 2; ++i) {
                int idx = t + i * 256;          // float4 index, 0..511
                int k = idx >> 5;               // 0..15
                int n4 = (idx & 31) * 4;
                float4 w = *(const float4*)&W1[(k0 + k) * HID + n4];
                float s = sig[k0 + k];
                Wl[k][n4 + 0] = w.x * s; Wl[k][n4 + 1] = w.y * s;
                Wl[k][n4 + 2] = w.z * s; Wl[k][n4 + 3] = w.w * s;
            }
        }
        __syncthreads();
#pragma unroll
        for (int k = 0; k < 16; ++k) {
            float xv[8], wv[4];
            *(float4*)&xv[0] = *(const float4*)&xT[k][tm * 8];
            *(float4*)&xv[4] = *(const float4*)&xT[k][tm * 8 + 4];
            *(float4*)&wv[0] = *(const float4*)&Wl[k][tn * 4];
#pragma unroll
            for (int i = 0; i < 8; ++i)
#pragma unroll
                for (int j = 0; j < 4; ++j)
                    acc[i][j] += xv[i] * wv[j];
        }
        __syncthreads();
    }
#pragma unroll
    for (int i = 0; i < 8; ++i) {
        int row = mbase + tm * 8 + i;
        if (row < N_NODES) {
            float d = dinv[row];
            float4 v = make_float4(acc[i][0] * d, acc[i][1] * d, acc[i][2] * d, acc[i][3] * d);
            *(float4*)&hs[row * HID + tn * 4] = v;
        }
    }
}

// ---------------- agg1 (CSR gather) fused with self-loop + dinv + b1 + BN stats ----------------
// one wave per node (grid-strided); lane owns channels 2l, 2l+1

__global__ __launch_bounds__(256) void k_agg1csr(const int* __restrict__ esrc,
                                                 const unsigned* __restrict__ rowptr,
                                                 const float* __restrict__ hs,
                                                 const float* __restrict__ dinv,
                                                 const float* __restrict__ b1,
                                                 float* __restrict__ S1,
                                                 float* __restrict__ stats) {
    const int t = threadIdx.x;
    const int lane = t & 63;
    const int gw = (blockIdx.x * blockDim.x + t) >> 6;
    const int nw = (gridDim.x * blockDim.x) >> 6;
    const int ch = lane * 2;
    const float2 bb = *(const float2*)&b1[ch];
    float s0 = 0.f, s1 = 0.f, q0 = 0.f, q1 = 0.f;

    for (int c = gw; c < N_NODES; c += nw) {
        unsigned beg = rowptr[c], end = rowptr[c + 1];
        float2 acc = *(const float2*)&hs[(size_t)c * HID + ch];   // self-loop term
        for (unsigned base = beg; base < end; base += 64) {
            int n = (int)min(64u, end - base);
            int my = (lane < n) ? esrc[base + lane] : 0;
#pragma unroll 4
            for (int i = 0; i < n; ++i) {
                int r = __shfl(my, i);
                float2 v = *(const float2*)&hs[(size_t)r * HID + ch];
                acc.x += v.x; acc.y += v.y;
            }
        }
        float d = dinv[c];
        float v0 = d * acc.x + bb.x;
        float v1 = d * acc.y + bb.y;
        *(float2*)&S1[(size_t)c * HID + ch] = make_float2(v0, v1);
        s0 += v0; s1 += v1; q0 += v0 * v0; q1 += v1 * v1;
    }

    // block-level reduce (4 waves share channel mapping), then one atomic set per block
    __shared__ float red[256];
#define RED_ATOMIC(val, idx)                                              \
    red[t] = (val); __syncthreads();                                      \
    if (t < 64) {                                                         \
        float r_ = red[t] + red[t + 64] + red[t + 128] + red[t + 192];    \
        atomicAdd(&stats[idx], r_);                                       \
    } __syncthreads();
    RED_ATOMIC(s0, ch)
    RED_ATOMIC(s1, ch + 1)
    RED_ATOMIC(q0, 128 + ch)
    RED_ATOMIC(q1, 129 + ch)
#undef RED_ATOMIC
}

// ---------------- BN finalize: scale/shift per channel ----------------

__global__ void k_bnfin(const float* __restrict__ stats,
                        const float* __restrict__ gamma,
                        const float* __restrict__ beta,
                        float* __restrict__ bnp) {
    int j = threadIdx.x;
    if (j < HID) {
        float mu = stats[j] * (1.0f / N_NODES);
        float var = stats[128 + j] * (1.0f / N_NODES) - mu * mu;
        float rstd = rsqrtf(var + BN_EPS);
        float sc = rstd * gamma[j];
        bnp[j] = sc;
        bnp[128 + j] = beta[j] - mu * sc;
    }
}

// ---------------- GEMM2 fused: gs[n][0:2] = dinv[n] * relu(bn(S1[n])) @ W2 ----------------

__global__ __launch_bounds__(256) void k_gemm2(const float* __restrict__ S1,
                                               const float* __restrict__ bnp,
                                               const float* __restrict__ W2,
                                               const float* __restrict__ dinv,
                                               float* __restrict__ gs) {
    int wid = (blockIdx.x * blockDim.x + threadIdx.x) >> 6;
    int lane = threadIdx.x & 63;
    int nw = (gridDim.x * blockDim.x) >> 6;
    int k0 = lane * 2;
    float2 sc = *(const float2*)&bnp[k0];
    float2 sh = *(const float2*)&bnp[128 + k0];
    float4 w = *(const float4*)&W2[k0 * 2];  // W2[k0][0..1], W2[k0+1][0..1]
    for (int n = wid; n < N_NODES; n += nw) {
        float2 h = *(const float2*)&S1[(size_t)n * HID + k0];
        float v0 = fmaxf(h.x * sc.x + sh.x, 0.f);
        float v1 = fmaxf(h.y * sc.y + sh.y, 0.f);
        float a0 = v0 * w.x + v1 * w.z;
        float a1 = v0 * w.y + v1 * w.w;
#pragma unroll
        for (int off = 32; off; off >>= 1) {
            a0 += __shfl_down(a0, off);
            a1 += __shfl_down(a1, off);
        }
        if (lane == 0) {
            float d = dinv[n];
            *(float2*)&gs[n * 2] = make_float2(a0 * d, a1 * d);
        }
    }
}

// ---------------- agg2 (CSR gather, thread per node) fused with self-loop + dinv + b2 ----------------

__global__ void k_agg2csr(const int* __restrict__ esrc,
                          const unsigned* __restrict__ rowptr,
                          const float* __restrict__ gs,
                          const float* __restrict__ dinv,
                          const float* __restrict__ b2,
                          float* __restrict__ out) {
    int c = blockIdx.x * blockDim.x + threadIdx.x;
    if (c >= N_NODES) return;
    float2 acc = *(const float2*)&gs[c * 2];   // self-loop
    unsigned beg = rowptr[c], end = rowptr[c + 1];
    for (unsigned i = beg; i < end; ++i) {
        int r = esrc[i];
        float2 v = *(const float2*)&gs[r * 2];
        acc.x += v.x; acc.y += v.y;
    }
    float d = dinv[c];
    *(float2*)&out[c * 2] = make_float2(d * acc.x + b2[0], d * acc.y + b2[1]);
}

// ---------------- launch ----------------

extern "C" void kernel_launch(void* const* d_in, const int* in_sizes, int n_in,
                              void* d_out, int out_size, void* d_ws, size_t ws_size,
                              hipStream_t stream) {
    const float* x     = (const float*)d_in[0];
    const int*   edge  = (const int*)d_in[1];      // [2, E]: row = edge[0..E), col = edge[E..2E)
    const float* fi    = (const float*)d_in[2];
    const float* W1    = (const float*)d_in[3];
    const float* b1    = (const float*)d_in[4];
    const float* W2    = (const float*)d_in[5];
    const float* b2    = (const float*)d_in[6];
    const float* gamma = (const float*)d_in[7];
    const float* beta  = (const float*)d_in[8];
    float* out = (float*)d_out;

    const int* erow = edge;
    const int* ecol = edge + N_EDGES;

    // workspace layout (256B aligned), ~118 MB total
    char* ws = (char*)d_ws;
    size_t off = 0;
    auto alloc = [&](size_t bytes) { size_t r = off; off = (off + bytes + 255) & ~(size_t)255; return r; };
    float*    hs    = (float*)(ws + alloc(sizeof(float) * (size_t)N_NODES * HID));   // 51.2 MB
    float*    S1    = (float*)(ws + alloc(sizeof(float) * (size_t)N_NODES * HID));   // 51.2 MB
    int*      esrc  = (int*)(ws + alloc(sizeof(int) * (size_t)N_EDGES));             // 12.8 MB
    float*    gs    = (float*)(ws + alloc(sizeof(float) * N_NODES * 2));             // 0.8 MB
    unsigned* cnt   = (unsigned*)(ws + alloc(sizeof(unsigned) * N_NODES));           // 0.4 MB
    unsigned* fill  = (unsigned*)(ws + alloc(sizeof(unsigned) * N_NODES));           // 0.4 MB
    unsigned* rowptr= (unsigned*)(ws + alloc(sizeof(unsigned) * (N_NODES + 1)));     // 0.4 MB
    unsigned* bsum  = (unsigned*)(ws + alloc(sizeof(unsigned) * NB1));
    unsigned* boff  = (unsigned*)(ws + alloc(sizeof(unsigned) * NB1));
    float*    dinv  = (float*)(ws + alloc(sizeof(float) * N_NODES));                 // 0.4 MB
    float*    sig   = (float*)(ws + alloc(sizeof(float) * IN_DIM));
    float*    stats = (float*)(ws + alloc(sizeof(float) * 2 * HID));
    float*    bnp   = (float*)(ws + alloc(sizeof(float) * 2 * HID));
    (void)ws_size; (void)in_sizes; (void)n_in; (void)out_size;

    hipMemsetAsync(cnt, 0, sizeof(unsigned) * N_NODES, stream);
    hipMemsetAsync(fill, 0, sizeof(unsigned) * N_NODES, stream);
    hipMemsetAsync(stats, 0, sizeof(float) * 2 * HID, stream);

    k_deg<<<(N_EDGES + 255) / 256, 256, 0, stream>>>(ecol, cnt);
    k_dinv<<<(N_NODES + 255) / 256, 256, 0, stream>>>(cnt, dinv);
    k_sig<<<1, 256, 0, stream>>>(fi, sig);

    k_scan_part<<<NB1, SCAN_B, 0, stream>>>(cnt, rowptr, bsum);
    k_scan_mid<<<1, 128, 0, stream>>>(bsum, boff);
    k_scan_add<<<(N_NODES + 255) / 256, 256, 0, stream>>>(rowptr, boff);
    k_bucket<<<(N_EDGES + 255) / 256, 256, 0, stream>>>(erow, ecol, rowptr, fill, esrc);

    k_gemm1<<<(N_NODES + 63) / 64, 256, 0, stream>>>(x, W1, sig, dinv, hs);
    k_agg1csr<<<2048, 256, 0, stream>>>(esrc, rowptr, hs, dinv, b1, S1, stats);
    k_bnfin<<<1, 128, 0, stream>>>(stats, gamma, beta, bnp);
    k_gemm2<<<2048, 256, 0, stream>>>(S1, bnp, W2, dinv, gs);
    k_agg2csr<<<(N_NODES + 255) / 256, 256, 0, stream>>>(esrc, rowptr, gs, dinv, b2, out);
}

// Round 3
// 822.378 us; speedup vs baseline: 4.0818x; 1.0890x over previous
//
#include <hip/hip_runtime.h>
#include <hip/hip_bf16.h>

#define N_NODES 100000
#define N_EDGES 3200000
#define IN_DIM 256
#define HID 128
#define BN_EPS 1e-5f
#define SCAN_B 1024
#define NB1 ((N_NODES + SCAN_B - 1) / SCAN_B)   // 98

typedef __attribute__((ext_vector_type(8))) short bf16x8;
typedef __attribute__((ext_vector_type(4))) float f32x4;

__device__ __forceinline__ ushort f2bf(float f) {      // round-to-nearest-even
    unsigned u = __float_as_uint(f);
    u += 0x7FFFu + ((u >> 16) & 1u);
    return (ushort)(u >> 16);
}
__device__ __forceinline__ float bflo(unsigned v) { return __uint_as_float(v << 16); }
__device__ __forceinline__ float bfhi(unsigned v) { return __uint_as_float(v & 0xFFFF0000u); }

// ---------------- degree / dinv / sigmoid / W1 transpose ----------------

__global__ void k_deg(const int* __restrict__ col, unsigned* __restrict__ cnt) {
    int i = blockIdx.x * blockDim.x + threadIdx.x;
    if (i < N_EDGES) atomicAdd(&cnt[col[i]], 1u);
}

__global__ void k_dinv(const unsigned* __restrict__ cnt, float* __restrict__ dinv) {
    int i = blockIdx.x * blockDim.x + threadIdx.x;
    if (i < N_NODES) dinv[i] = rsqrtf((float)(cnt[i] + 1u));  // +1 self-loop
}

__global__ void k_sig(const float* __restrict__ fi, float* __restrict__ sig) {
    int i = threadIdx.x;
    if (i < IN_DIM) sig[i] = 1.0f / (1.0f + expf(-fi[i]));
}

// W1t[n][k] = bf16(W1[k][n] * sig[k])   (128 x 256 bf16, 64 KB)
__global__ void k_prepw(const float* __restrict__ W1, const float* __restrict__ sig,
                        ushort* __restrict__ W1t) {
    int idx = blockIdx.x * blockDim.x + threadIdx.x;
    if (idx < HID * IN_DIM) {
        int n = idx >> 8, k = idx & 255;
        W1t[idx] = f2bf(W1[k * HID + n] * sig[k]);
    }
}

// ---------------- exclusive prefix scan of cnt -> rowptr ----------------

__global__ __launch_bounds__(SCAN_B) void k_scan_part(const unsigned* __restrict__ cnt,
                                                      unsigned* __restrict__ rowptr,
                                                      unsigned* __restrict__ blocksum) {
    __shared__ unsigned s[SCAN_B];
    int t = threadIdx.x;
    int i = blockIdx.x * SCAN_B + t;
    unsigned v = (i < N_NODES) ? cnt[i] : 0u;
    s[t] = v;
    __syncthreads();
#pragma unroll
    for (int off = 1; off < SCAN_B; off <<= 1) {
        unsigned u = (t >= off) ? s[t - off] : 0u;
        __syncthreads();
        s[t] += u;
        __syncthreads();
    }
    if (i < N_NODES) rowptr[i] = s[t] - v;
    if (t == SCAN_B - 1) blocksum[blockIdx.x] = s[t];
}

__global__ __launch_bounds__(128) void k_scan_mid(const unsigned* __restrict__ blocksum,
                                                  unsigned* __restrict__ blockoff) {
    __shared__ unsigned s[128];
    int t = threadIdx.x;
    unsigned v = (t < NB1) ? blocksum[t] : 0u;
    s[t] = v;
    __syncthreads();
#pragma unroll
    for (int off = 1; off < 128; off <<= 1) {
        unsigned u = (t >= off) ? s[t - off] : 0u;
        __syncthreads();
        s[t] += u;
        __syncthreads();
    }
    if (t < NB1) blockoff[t] = s[t] - v;
}

__global__ void k_scan_add(unsigned* __restrict__ rowptr, const unsigned* __restrict__ blockoff) {
    int i = blockIdx.x * blockDim.x + threadIdx.x;
    if (i < N_NODES) rowptr[i] += blockoff[i >> 10];
    if (i == 0) rowptr[N_NODES] = N_EDGES;
}

// ---------------- bucket: esrc sorted by destination ----------------

__global__ void k_bucket(const int* __restrict__ row, const int* __restrict__ col,
                         const unsigned* __restrict__ rowptr, unsigned* __restrict__ fill,
                         int* __restrict__ esrc) {
    int e = blockIdx.x * blockDim.x + threadIdx.x;
    if (e < N_EDGES) {
        int c = col[e];
        unsigned p = rowptr[c] + atomicAdd(&fill[c], 1u);
        esrc[p] = row[e];
    }
}

// ---------------- GEMM1 (MFMA bf16): hs[m][n] = dinv[m]*sum_k xbf[m][k]*W1t[n][k] ----------------
// One wave computes a 16-node x 128-channel strip. D[i=channel][j=node]:
//   A-frag: W1t[nb*16 + (l&15)][ks*32 + (l>>4)*8 + 0..7]  (16B contiguous)
//   B-frag: x  [m0    + (l&15)][ks*32 + (l>>4)*8 + 0..7]  (fp32 -> bf16 in reg)
//   D: lane l holds node m0+(l&15), channels nb*16 + (l>>4)*4 + r
// hs packed bf16x2 per uint (row = 64 uints).

__global__ __launch_bounds__(256) void k_gemm1(const float* __restrict__ x,
                                               const ushort* __restrict__ W1t,
                                               const float* __restrict__ dinv,
                                               unsigned* __restrict__ hsu) {
    const int t = threadIdx.x;
    const int w = (blockIdx.x << 2) + (t >> 6);
    const int m0 = w << 4;
    if (m0 >= N_NODES) return;
    const int lane = t & 63;
    const int mrow = lane & 15;
    const int quad = lane >> 4;

    const float* xrow = x + (size_t)(m0 + mrow) * IN_DIM + quad * 8;
    const ushort* wrow = W1t + mrow * IN_DIM + quad * 8;

    f32x4 acc[8] = {};
#pragma unroll
    for (int ks = 0; ks < 8; ++ks) {
        float4 xa = *(const float4*)(xrow + ks * 32);
        float4 xb = *(const float4*)(xrow + ks * 32 + 4);
        bf16x8 bfrag;
        bfrag[0] = (short)f2bf(xa.x); bfrag[1] = (short)f2bf(xa.y);
        bfrag[2] = (short)f2bf(xa.z); bfrag[3] = (short)f2bf(xa.w);
        bfrag[4] = (short)f2bf(xb.x); bfrag[5] = (short)f2bf(xb.y);
        bfrag[6] = (short)f2bf(xb.z); bfrag[7] = (short)f2bf(xb.w);
        const ushort* wk = wrow + ks * 32;
#pragma unroll
        for (int nb = 0; nb < 8; ++nb) {
            bf16x8 afrag = *(const bf16x8*)(wk + nb * 16 * IN_DIM);
            acc[nb] = __builtin_amdgcn_mfma_f32_16x16x32_bf16(afrag, bfrag, acc[nb], 0, 0, 0);
        }
    }
    const float d = dinv[m0 + mrow];
    unsigned* orow = hsu + (size_t)(m0 + mrow) * 64;
#pragma unroll
    for (int nb = 0; nb < 8; ++nb) {
        unsigned p0 = (unsigned)f2bf(acc[nb][0] * d) | ((unsigned)f2bf(acc[nb][1] * d) << 16);
        unsigned p1 = (unsigned)f2bf(acc[nb][2] * d) | ((unsigned)f2bf(acc[nb][3] * d) << 16);
        *(uint2*)(orow + nb * 8 + quad * 2) = make_uint2(p0, p1);
    }
}

// ---------------- agg1 (CSR gather, bf16) + self-loop + dinv + b1 + BN stats ----------------

__global__ __launch_bounds__(256) void k_agg1csr(const int* __restrict__ esrc,
                                                 const unsigned* __restrict__ rowptr,
                                                 const unsigned* __restrict__ hsu,
                                                 const float* __restrict__ dinv,
                                                 const float* __restrict__ b1,
                                                 float* __restrict__ S1,
                                                 float* __restrict__ stats) {
    const int t = threadIdx.x;
    const int lane = t & 63;
    const int gw = (blockIdx.x * blockDim.x + t) >> 6;
    const int nw = (gridDim.x * blockDim.x) >> 6;
    const int ch = lane * 2;
    const float2 bb = *(const float2*)&b1[ch];
    float s0 = 0.f, s1 = 0.f, q0 = 0.f, q1 = 0.f;

    for (int c = gw; c < N_NODES; c += nw) {
        unsigned beg = rowptr[c], end = rowptr[c + 1];
        unsigned self = hsu[(size_t)c * 64 + lane];
        float a0 = bflo(self), a1 = bfhi(self);
        for (unsigned base = beg; base < end; base += 64) {
            int n = (int)min(64u, end - base);
            int my = (lane < n) ? esrc[base + lane] : 0;
#pragma unroll 4
            for (int i = 0; i < n; ++i) {
                int r = __shfl(my, i);
                unsigned v = hsu[(size_t)r * 64 + lane];
                a0 += bflo(v); a1 += bfhi(v);
            }
        }
        float d = dinv[c];
        float v0 = d * a0 + bb.x;
        float v1 = d * a1 + bb.y;
        *(float2*)&S1[(size_t)c * HID + ch] = make_float2(v0, v1);
        s0 += v0; s1 += v1; q0 += v0 * v0; q1 += v1 * v1;
    }

    __shared__ float red[256];
#define RED_ATOMIC(val, idx)                                              \
    red[t] = (val); __syncthreads();                                      \
    if (t < 64) {                                                         \
        float r_ = red[t] + red[t + 64] + red[t + 128] + red[t + 192];    \
        atomicAdd(&stats[idx], r_);                                       \
    } __syncthreads();
    RED_ATOMIC(s0, ch)
    RED_ATOMIC(s1, ch + 1)
    RED_ATOMIC(q0, 128 + ch)
    RED_ATOMIC(q1, 129 + ch)
#undef RED_ATOMIC
}

// ---------------- BN finalize ----------------

__global__ void k_bnfin(const float* __restrict__ stats,
                        const float* __restrict__ gamma,
                        const float* __restrict__ beta,
                        float* __restrict__ bnp) {
    int j = threadIdx.x;
    if (j < HID) {
        float mu = stats[j] * (1.0f / N_NODES);
        float var = stats[128 + j] * (1.0f / N_NODES) - mu * mu;
        float rstd = rsqrtf(var + BN_EPS);
        float sc = rstd * gamma[j];
        bnp[j] = sc;
        bnp[128 + j] = beta[j] - mu * sc;
    }
}

// ---------------- GEMM2 fused: gs[n][0:2] = dinv[n] * relu(bn(S1[n])) @ W2 ----------------

__global__ __launch_bounds__(256) void k_gemm2(const float* __restrict__ S1,
                                               const float* __restrict__ bnp,
                                               const float* __restrict__ W2,
                                               const float* __restrict__ dinv,
                                               float* __restrict__ gs) {
    int wid = (blockIdx.x * blockDim.x + threadIdx.x) >> 6;
    int lane = threadIdx.x & 63;
    int nw = (gridDim.x * blockDim.x) >> 6;
    int k0 = lane * 2;
    float2 sc = *(const float2*)&bnp[k0];
    float2 sh = *(const float2*)&bnp[128 + k0];
    float4 w = *(const float4*)&W2[k0 * 2];
    for (int n = wid; n < N_NODES; n += nw) {
        float2 h = *(const float2*)&S1[(size_t)n * HID + k0];
        float v0 = fmaxf(h.x * sc.x + sh.x, 0.f);
        float v1 = fmaxf(h.y * sc.y + sh.y, 0.f);
        float a0 = v0 * w.x + v1 * w.z;
        float a1 = v0 * w.y + v1 * w.w;
#pragma unroll
        for (int off = 32; off; off >>= 1) {
            a0 += __shfl_down(a0, off);
            a1 += __shfl_down(a1, off);
        }
        if (lane == 0) {
            float d = dinv[n];
            *(float2*)&gs[n * 2] = make_float2(a0 * d, a1 * d);
        }
    }
}

// ---------------- agg2 (CSR gather, thread per node) + self-loop + dinv + b2 ----------------

__global__ void k_agg2csr(const int* __restrict__ esrc,
                          const unsigned* __restrict__ rowptr,
                          const float* __restrict__ gs,
                          const float* __restrict__ dinv,
                          const float* __restrict__ b2,
                          float* __restrict__ out) {
    int c = blockIdx.x * blockDim.x + threadIdx.x;
    if (c >= N_NODES) return;
    float2 acc = *(const float2*)&gs[c * 2];
    unsigned beg = rowptr[c], end = rowptr[c + 1];
    for (unsigned i = beg; i < end; ++i) {
        int r = esrc[i];
        float2 v = *(const float2*)&gs[r * 2];
        acc.x += v.x; acc.y += v.y;
    }
    float d = dinv[c];
    *(float2*)&out[c * 2] = make_float2(d * acc.x + b2[0], d * acc.y + b2[1]);
}

// ---------------- launch ----------------

extern "C" void kernel_launch(void* const* d_in, const int* in_sizes, int n_in,
                              void* d_out, int out_size, void* d_ws, size_t ws_size,
                              hipStream_t stream) {
    const float* x     = (const float*)d_in[0];
    const int*   edge  = (const int*)d_in[1];      // [2, E]: row = edge[0..E), col = edge[E..2E)
    const float* fi    = (const float*)d_in[2];
    const float* W1    = (const float*)d_in[3];
    const float* b1    = (const float*)d_in[4];
    const float* W2    = (const float*)d_in[5];
    const float* b2    = (const float*)d_in[6];
    const float* gamma = (const float*)d_in[7];
    const float* beta  = (const float*)d_in[8];
    float* out = (float*)d_out;

    const int* erow = edge;
    const int* ecol = edge + N_EDGES;

    char* ws = (char*)d_ws;
    size_t off = 0;
    auto alloc = [&](size_t bytes) { size_t r = off; off = (off + bytes + 255) & ~(size_t)255; return r; };
    unsigned* hsu   = (unsigned*)(ws + alloc(sizeof(unsigned) * (size_t)N_NODES * 64)); // 25.6 MB (bf16x2)
    float*    S1    = (float*)(ws + alloc(sizeof(float) * (size_t)N_NODES * HID));      // 51.2 MB
    int*      esrc  = (int*)(ws + alloc(sizeof(int) * (size_t)N_EDGES));                // 12.8 MB
    float*    gs    = (float*)(ws + alloc(sizeof(float) * N_NODES * 2));                // 0.8 MB
    unsigned* cnt   = (unsigned*)(ws + alloc(sizeof(unsigned) * N_NODES));
    unsigned* fill  = (unsigned*)(ws + alloc(sizeof(unsigned) * N_NODES));
    unsigned* rowptr= (unsigned*)(ws + alloc(sizeof(unsigned) * (N_NODES + 1)));
    unsigned* bsum  = (unsigned*)(ws + alloc(sizeof(unsigned) * NB1));
    unsigned* boff  = (unsigned*)(ws + alloc(sizeof(unsigned) * NB1));
    float*    dinv  = (float*)(ws + alloc(sizeof(float) * N_NODES));
    float*    sig   = (float*)(ws + alloc(sizeof(float) * IN_DIM));
    ushort*   W1t   = (ushort*)(ws + alloc(sizeof(ushort) * HID * IN_DIM));             // 64 KB
    float*    stats = (float*)(ws + alloc(sizeof(float) * 2 * HID));
    float*    bnp   = (float*)(ws + alloc(sizeof(float) * 2 * HID));
    (void)ws_size; (void)in_sizes; (void)n_in; (void)out_size;

    hipMemsetAsync(cnt, 0, sizeof(unsigned) * N_NODES, stream);
    hipMemsetAsync(fill, 0, sizeof(unsigned) * N_NODES, stream);
    hipMemsetAsync(stats, 0, sizeof(float) * 2 * HID, stream);

    k_deg<<<(N_EDGES + 255) / 256, 256, 0, stream>>>(ecol, cnt);
    k_dinv<<<(N_NODES + 255) / 256, 256, 0, stream>>>(cnt, dinv);
    k_sig<<<1, 256, 0, stream>>>(fi, sig);
    k_prepw<<<(HID * IN_DIM + 255) / 256, 256, 0, stream>>>(W1, sig, W1t);

    k_scan_part<<<NB1, SCAN_B, 0, stream>>>(cnt, rowptr, bsum);
    k_scan_mid<<<1, 128, 0, stream>>>(bsum, boff);
    k_scan_add<<<(N_NODES + 255) / 256, 256, 0, stream>>>(rowptr, boff);
    k_bucket<<<(N_EDGES + 255) / 256, 256, 0, stream>>>(erow, ecol, rowptr, fill, esrc);

    k_gemm1<<<(N_NODES / 16 + 3) / 4, 256, 0, stream>>>(x, W1t, dinv, hsu);
    k_agg1csr<<<2048, 256, 0, stream>>>(esrc, rowptr, hsu, dinv, b1, S1, stats);
    k_bnfin<<<1, 128, 0, stream>>>(stats, gamma, beta, bnp);
    k_gemm2<<<2048, 256, 0, stream>>>(S1, bnp, W2, dinv, gs);
    k_agg2csr<<<(N_NODES + 255) / 256, 256, 0, stream>>>(esrc, rowptr, gs, dinv, b2, out);
}

// Round 5
// 747.483 us; speedup vs baseline: 4.4908x; 1.1002x over previous
//
#include <hip/hip_runtime.h>
#include <hip/hip_bf16.h>

#define N_NODES 100000
#define N_EDGES 3200000
#define IN_DIM 256
#define HID 128
#define BN_EPS 1e-5f
#define SCAN_B 1024
#define NB1 ((N_NODES + SCAN_B - 1) / SCAN_B)   // 98

typedef __attribute__((ext_vector_type(8))) short bf16x8;
typedef __attribute__((ext_vector_type(4))) float f32x4;

__device__ __forceinline__ ushort f2bf(float f) {      // round-to-nearest-even
    unsigned u = __float_as_uint(f);
    u += 0x7FFFu + ((u >> 16) & 1u);
    return (ushort)(u >> 16);
}
__device__ __forceinline__ float bflo(unsigned v) { return __uint_as_float(v << 16); }
__device__ __forceinline__ float bfhi(unsigned v) { return __uint_as_float(v & 0xFFFF0000u); }

// ---------------- degree ----------------

__global__ void k_deg(const int* __restrict__ col, unsigned* __restrict__ cnt) {
    int i = blockIdx.x * blockDim.x + threadIdx.x;
    if (i < N_EDGES) atomicAdd(&cnt[col[i]], 1u);
}

// W1t[n][k] = bf16(W1[k][n] * sigmoid(fi[k]))   (128 x 256 bf16, 64 KB)
__global__ void k_prepw(const float* __restrict__ W1, const float* __restrict__ fi,
                        ushort* __restrict__ W1t) {
    int idx = blockIdx.x * blockDim.x + threadIdx.x;
    if (idx < HID * IN_DIM) {
        int n = idx >> 8, k = idx & 255;
        float s = 1.0f / (1.0f + expf(-fi[k]));
        W1t[idx] = f2bf(W1[k * HID + n] * s);
    }
}

// ---------------- exclusive prefix scan of cnt -> rowptr (+ dinv fused) ----------------

__global__ __launch_bounds__(SCAN_B) void k_scan_part(const unsigned* __restrict__ cnt,
                                                      unsigned* __restrict__ rowptr,
                                                      unsigned* __restrict__ blocksum,
                                                      float* __restrict__ dinv) {
    __shared__ unsigned s[SCAN_B];
    int t = threadIdx.x;
    int i = blockIdx.x * SCAN_B + t;
    unsigned v = (i < N_NODES) ? cnt[i] : 0u;
    if (i < N_NODES) dinv[i] = rsqrtf((float)(v + 1u));   // +1 self-loop
    s[t] = v;
    __syncthreads();
#pragma unroll
    for (int off = 1; off < SCAN_B; off <<= 1) {
        unsigned u = (t >= off) ? s[t - off] : 0u;
        __syncthreads();
        s[t] += u;
        __syncthreads();
    }
    if (i < N_NODES) rowptr[i] = s[t] - v;
    if (t == SCAN_B - 1) blocksum[blockIdx.x] = s[t];
}

__global__ __launch_bounds__(128) void k_scan_mid(const unsigned* __restrict__ blocksum,
                                                  unsigned* __restrict__ blockoff) {
    __shared__ unsigned s[128];
    int t = threadIdx.x;
    unsigned v = (t < NB1) ? blocksum[t] : 0u;
    s[t] = v;
    __syncthreads();
#pragma unroll
    for (int off = 1; off < 128; off <<= 1) {
        unsigned u = (t >= off) ? s[t - off] : 0u;
        __syncthreads();
        s[t] += u;
        __syncthreads();
    }
    if (t < NB1) blockoff[t] = s[t] - v;
}

__global__ void k_scan_add(unsigned* __restrict__ rowptr, const unsigned* __restrict__ blockoff) {
    int i = blockIdx.x * blockDim.x + threadIdx.x;
    if (i < N_NODES) rowptr[i] += blockoff[i >> 10];
    if (i == 0) rowptr[N_NODES] = N_EDGES;
}

// ---------------- bucket: esrc sorted by destination ----------------

__global__ void k_bucket(const int* __restrict__ row, const int* __restrict__ col,
                         const unsigned* __restrict__ rowptr, unsigned* __restrict__ fill,
                         int* __restrict__ esrc) {
    int e = blockIdx.x * blockDim.x + threadIdx.x;
    if (e < N_EDGES) {
        int c = col[e];
        unsigned p = rowptr[c] + atomicAdd(&fill[c], 1u);
        esrc[p] = row[e];
    }
}

// ---------------- GEMM1 (MFMA bf16): hs[m][n] = dinv[m]*sum_k xbf[m][k]*W1t[n][k] ----------------

__global__ __launch_bounds__(256) void k_gemm1(const float* __restrict__ x,
                                               const ushort* __restrict__ W1t,
                                               const float* __restrict__ dinv,
                                               unsigned* __restrict__ hsu) {
    const int t = threadIdx.x;
    const int w = (blockIdx.x << 2) + (t >> 6);
    const int m0 = w << 4;
    if (m0 >= N_NODES) return;
    const int lane = t & 63;
    const int mrow = lane & 15;
    const int quad = lane >> 4;

    const float* xrow = x + (size_t)(m0 + mrow) * IN_DIM + quad * 8;
    const ushort* wrow = W1t + mrow * IN_DIM + quad * 8;

    f32x4 acc[8] = {};
#pragma unroll
    for (int ks = 0; ks < 8; ++ks) {
        float4 xa = *(const float4*)(xrow + ks * 32);
        float4 xb = *(const float4*)(xrow + ks * 32 + 4);
        bf16x8 bfrag;
        bfrag[0] = (short)f2bf(xa.x); bfrag[1] = (short)f2bf(xa.y);
        bfrag[2] = (short)f2bf(xa.z); bfrag[3] = (short)f2bf(xa.w);
        bfrag[4] = (short)f2bf(xb.x); bfrag[5] = (short)f2bf(xb.y);
        bfrag[6] = (short)f2bf(xb.z); bfrag[7] = (short)f2bf(xb.w);
        const ushort* wk = wrow + ks * 32;
#pragma unroll
        for (int nb = 0; nb < 8; ++nb) {
            bf16x8 afrag = *(const bf16x8*)(wk + nb * 16 * IN_DIM);
            acc[nb] = __builtin_amdgcn_mfma_f32_16x16x32_bf16(afrag, bfrag, acc[nb], 0, 0, 0);
        }
    }
    const float d = dinv[m0 + mrow];
    unsigned* orow = hsu + (size_t)(m0 + mrow) * 64;
#pragma unroll
    for (int nb = 0; nb < 8; ++nb) {
        unsigned p0 = (unsigned)f2bf(acc[nb][0] * d) | ((unsigned)f2bf(acc[nb][1] * d) << 16);
        unsigned p1 = (unsigned)f2bf(acc[nb][2] * d) | ((unsigned)f2bf(acc[nb][3] * d) << 16);
        *(uint2*)(orow + nb * 8 + quad * 2) = make_uint2(p0, p1);
    }
}

// ---------------- agg1 (CSR gather, uniform source broadcast) + BN stats; S1 bf16 ----------------

__global__ __launch_bounds__(256) void k_agg1csr(const int* __restrict__ esrc,
                                                 const unsigned* __restrict__ rowptr,
                                                 const unsigned* __restrict__ hsu,
                                                 const float* __restrict__ dinv,
                                                 const float* __restrict__ b1,
                                                 unsigned* __restrict__ S1u,
                                                 float* __restrict__ stats) {
    const int t = threadIdx.x;
    const int lane = t & 63;
    const int gw = (blockIdx.x * blockDim.x + t) >> 6;
    const int nw = (gridDim.x * blockDim.x) >> 6;
    const int ch = lane * 2;
    const float2 bb = *(const float2*)&b1[ch];
    float s0 = 0.f, s1 = 0.f, q0 = 0.f, q1 = 0.f;

    for (int c = gw; c < N_NODES; c += nw) {
        const unsigned beg = rowptr[c], end = rowptr[c + 1];
        unsigned self = hsu[(size_t)c * 64 + lane];
        float a0 = bflo(self), a1 = bfhi(self);
        unsigned i = beg;
        for (; i + 8 <= end; i += 8) {
#pragma unroll
            for (int u = 0; u < 8; ++u) {
                int r = esrc[i + u];                       // wave-uniform -> scalar load
                unsigned v = hsu[(size_t)r * 64 + lane];
                a0 += bflo(v); a1 += bfhi(v);
            }
        }
        for (; i < end; ++i) {
            int r = esrc[i];
            unsigned v = hsu[(size_t)r * 64 + lane];
            a0 += bflo(v); a1 += bfhi(v);
        }
        float d = dinv[c];
        float v0 = d * a0 + bb.x;
        float v1 = d * a1 + bb.y;
        S1u[(size_t)c * 64 + lane] = (unsigned)f2bf(v0) | ((unsigned)f2bf(v1) << 16);
        s0 += v0; s1 += v1; q0 += v0 * v0; q1 += v1 * v1;
    }

    __shared__ float red[256];
#define RED_ATOMIC(val, idx)                                              \
    red[t] = (val); __syncthreads();                                      \
    if (t < 64) {                                                         \
        float r_ = red[t] + red[t + 64] + red[t + 128] + red[t + 192];    \
        atomicAdd(&stats[idx], r_);                                       \
    } __syncthreads();
    RED_ATOMIC(s0, ch)
    RED_ATOMIC(s1, ch + 1)
    RED_ATOMIC(q0, 128 + ch)
    RED_ATOMIC(q1, 129 + ch)
#undef RED_ATOMIC
}

// ---------------- BN finalize ----------------

__global__ void k_bnfin(const float* __restrict__ stats,
                        const float* __restrict__ gamma,
                        const float* __restrict__ beta,
                        float* __restrict__ bnp) {
    int j = threadIdx.x;
    if (j < HID) {
        float mu = stats[j] * (1.0f / N_NODES);
        float var = stats[128 + j] * (1.0f / N_NODES) - mu * mu;
        float rstd = rsqrtf(var + BN_EPS);
        float sc = rstd * gamma[j];
        bnp[j] = sc;
        bnp[128 + j] = beta[j] - mu * sc;
    }
}

// ---------------- GEMM2 fused: gs[n][0:2] = dinv[n] * relu(bn(S1[n])) @ W2 ----------------

__global__ __launch_bounds__(256) void k_gemm2(const unsigned* __restrict__ S1u,
                                               const float* __restrict__ bnp,
                                               const float* __restrict__ W2,
                                               const float* __restrict__ dinv,
                                               float* __restrict__ gs) {
    int wid = (blockIdx.x * blockDim.x + threadIdx.x) >> 6;
    int lane = threadIdx.x & 63;
    int nw = (gridDim.x * blockDim.x) >> 6;
    int k0 = lane * 2;
    float2 sc = *(const float2*)&bnp[k0];
    float2 sh = *(const float2*)&bnp[128 + k0];
    float4 w = *(const float4*)&W2[k0 * 2];
    for (int n = wid; n < N_NODES; n += nw) {
        unsigned hv = S1u[(size_t)n * 64 + lane];
        float v0 = fmaxf(bflo(hv) * sc.x + sh.x, 0.f);
        float v1 = fmaxf(bfhi(hv) * sc.y + sh.y, 0.f);
        float a0 = v0 * w.x + v1 * w.z;
        float a1 = v0 * w.y + v1 * w.w;
#pragma unroll
        for (int off = 32; off; off >>= 1) {
            a0 += __shfl_down(a0, off);
            a1 += __shfl_down(a1, off);
        }
        if (lane == 0) {
            float d = dinv[n];
            *(float2*)&gs[n * 2] = make_float2(a0 * d, a1 * d);
        }
    }
}

// ---------------- agg2 (CSR gather, thread per node) + self-loop + dinv + b2 ----------------

__global__ void k_agg2csr(const int* __restrict__ esrc,
                          const unsigned* __restrict__ rowptr,
                          const float* __restrict__ gs,
                          const float* __restrict__ dinv,
                          const float* __restrict__ b2,
                          float* __restrict__ out) {
    int c = blockIdx.x * blockDim.x + threadIdx.x;
    if (c >= N_NODES) return;
    float2 acc = *(const float2*)&gs[c * 2];
    unsigned beg = rowptr[c], end = rowptr[c + 1];
    unsigned i = beg;
    for (; i + 4 <= end; i += 4) {
#pragma unroll
        for (int u = 0; u < 4; ++u) {
            int r = esrc[i + u];
            float2 v = *(const float2*)&gs[r * 2];
            acc.x += v.x; acc.y += v.y;
        }
    }
    for (; i < end; ++i) {
        int r = esrc[i];
        float2 v = *(const float2*)&gs[r * 2];
        acc.x += v.x; acc.y += v.y;
    }
    float d = dinv[c];
    *(float2*)&out[c * 2] = make_float2(d * acc.x + b2[0], d * acc.y + b2[1]);
}

// ---------------- launch ----------------

extern "C" void kernel_launch(void* const* d_in, const int* in_sizes, int n_in,
                              void* d_out, int out_size, void* d_ws, size_t ws_size,
                              hipStream_t stream) {
    const float* x     = (const float*)d_in[0];
    const int*   edge  = (const int*)d_in[1];      // [2, E]: row = edge[0..E), col = edge[E..2E)
    const float* fi    = (const float*)d_in[2];
    const float* W1    = (const float*)d_in[3];
    const float* b1    = (const float*)d_in[4];
    const float* W2    = (const float*)d_in[5];
    const float* b2    = (const float*)d_in[6];
    const float* gamma = (const float*)d_in[7];
    const float* beta  = (const float*)d_in[8];
    float* out = (float*)d_out;

    const int* erow = edge;
    const int* ecol = edge + N_EDGES;

    char* ws = (char*)d_ws;
    size_t off = 0;
    auto alloc = [&](size_t bytes) { size_t r = off; off = (off + bytes + 255) & ~(size_t)255; return r; };
    unsigned* hsu   = (unsigned*)(ws + alloc(sizeof(unsigned) * (size_t)N_NODES * 64)); // 25.6 MB
    unsigned* S1u   = (unsigned*)(ws + alloc(sizeof(unsigned) * (size_t)N_NODES * 64)); // 25.6 MB
    int*      esrc  = (int*)(ws + alloc(sizeof(int) * (size_t)N_EDGES));                // 12.8 MB
    float*    gs    = (float*)(ws + alloc(sizeof(float) * N_NODES * 2));                // 0.8 MB
    unsigned* cnt   = (unsigned*)(ws + alloc(sizeof(unsigned) * N_NODES * 2));          // cnt+fill adjacent
    unsigned* fill  = cnt + N_NODES;
    unsigned* rowptr= (unsigned*)(ws + alloc(sizeof(unsigned) * (N_NODES + 1)));
    unsigned* bsum  = (unsigned*)(ws + alloc(sizeof(unsigned) * NB1));
    unsigned* boff  = (unsigned*)(ws + alloc(sizeof(unsigned) * NB1));
    float*    dinv  = (float*)(ws + alloc(sizeof(float) * N_NODES));
    ushort*   W1t   = (ushort*)(ws + alloc(sizeof(ushort) * HID * IN_DIM));             // 64 KB
    float*    stats = (float*)(ws + alloc(sizeof(float) * 2 * HID));
    float*    bnp   = (float*)(ws + alloc(sizeof(float) * 2 * HID));
    (void)ws_size; (void)in_sizes; (void)n_in; (void)out_size;

    hipMemsetAsync(cnt, 0, sizeof(unsigned) * N_NODES * 2, stream);
    hipMemsetAsync(stats, 0, sizeof(float) * 2 * HID, stream);

    k_deg<<<(N_EDGES + 255) / 256, 256, 0, stream>>>(ecol, cnt);
    k_prepw<<<(HID * IN_DIM + 255) / 256, 256, 0, stream>>>(W1, fi, W1t);

    k_scan_part<<<NB1, SCAN_B, 0, stream>>>(cnt, rowptr, bsum, dinv);
    k_scan_mid<<<1, 128, 0, stream>>>(bsum, boff);
    k_scan_add<<<(N_NODES + 255) / 256, 256, 0, stream>>>(rowptr, boff);
    k_bucket<<<(N_EDGES + 255) / 256, 256, 0, stream>>>(erow, ecol, rowptr, fill, esrc);

    k_gemm1<<<(N_NODES / 16 + 3) / 4, 256, 0, stream>>>(x, W1t, dinv, hsu);
    k_agg1csr<<<2048, 256, 0, stream>>>(esrc, rowptr, hsu, dinv, b1, S1u, stats);
    k_bnfin<<<1, 128, 0, stream>>>(stats, gamma, beta, bnp);
    k_gemm2<<<2048, 256, 0, stream>>>(S1u, bnp, W2, dinv, gs);
    k_agg2csr<<<(N_NODES + 255) / 256, 256, 0, stream>>>(esrc, rowptr, gs, dinv, b2, out);
}

// Round 7
// 744.877 us; speedup vs baseline: 4.5065x; 1.0035x over previous
//
#include <hip/hip_runtime.h>
#include <hip/hip_bf16.h>

#define N_NODES 100000
#define N_EDGES 3200000
#define IN_DIM 256
#define HID 128
#define BN_EPS 1e-5f
#define SCAN_B 1024
#define NB1 ((N_NODES + SCAN_B - 1) / SCAN_B)   // 98

typedef __attribute__((ext_vector_type(8))) short bf16x8;
typedef __attribute__((ext_vector_type(4))) float f32x4;

__device__ __forceinline__ ushort f2bf(float f) {      // round-to-nearest-even
    unsigned u = __float_as_uint(f);
    u += 0x7FFFu + ((u >> 16) & 1u);
    return (ushort)(u >> 16);
}
__device__ __forceinline__ float bflo(unsigned v) { return __uint_as_float(v << 16); }
__device__ __forceinline__ float bfhi(unsigned v) { return __uint_as_float(v & 0xFFFF0000u); }

// ---------------- degree (int2-paired edge sweep) ----------------

__global__ void k_deg(const int* __restrict__ col, unsigned* __restrict__ cnt) {
    int i = blockIdx.x * blockDim.x + threadIdx.x;
    int e = i * 2;
    if (e + 1 < N_EDGES) {
        int2 cc = *(const int2*)&col[e];
        atomicAdd(&cnt[cc.x], 1u);
        atomicAdd(&cnt[cc.y], 1u);
    } else if (e < N_EDGES) {
        atomicAdd(&cnt[col[e]], 1u);
    }
}

// W1t[n][k] = bf16(W1[k][n] * sigmoid(fi[k]))   (128 x 256 bf16, 64 KB)
__global__ void k_prepw(const float* __restrict__ W1, const float* __restrict__ fi,
                        ushort* __restrict__ W1t) {
    int idx = blockIdx.x * blockDim.x + threadIdx.x;
    if (idx < HID * IN_DIM) {
        int n = idx >> 8, k = idx & 255;
        float s = 1.0f / (1.0f + expf(-fi[k]));
        W1t[idx] = f2bf(W1[k * HID + n] * s);
    }
}

// ---------------- exclusive prefix scan of cnt -> rowptr (+ dinv fused) ----------------

__global__ __launch_bounds__(SCAN_B) void k_scan_part(const unsigned* __restrict__ cnt,
                                                      unsigned* __restrict__ rowptr,
                                                      unsigned* __restrict__ blocksum,
                                                      float* __restrict__ dinv) {
    __shared__ unsigned s[SCAN_B];
    int t = threadIdx.x;
    int i = blockIdx.x * SCAN_B + t;
    unsigned v = (i < N_NODES) ? cnt[i] : 0u;
    if (i < N_NODES) dinv[i] = rsqrtf((float)(v + 1u));   // +1 self-loop
    s[t] = v;
    __syncthreads();
#pragma unroll
    for (int off = 1; off < SCAN_B; off <<= 1) {
        unsigned u = (t >= off) ? s[t - off] : 0u;
        __syncthreads();
        s[t] += u;
        __syncthreads();
    }
    if (i < N_NODES) rowptr[i] = s[t] - v;
    if (t == SCAN_B - 1) blocksum[blockIdx.x] = s[t];
}

__global__ __launch_bounds__(128) void k_scan_mid(const unsigned* __restrict__ blocksum,
                                                  unsigned* __restrict__ blockoff) {
    __shared__ unsigned s[128];
    int t = threadIdx.x;
    unsigned v = (t < NB1) ? blocksum[t] : 0u;
    s[t] = v;
    __syncthreads();
#pragma unroll
    for (int off = 1; off < 128; off <<= 1) {
        unsigned u = (t >= off) ? s[t - off] : 0u;
        __syncthreads();
        s[t] += u;
        __syncthreads();
    }
    if (t < NB1) blockoff[t] = s[t] - v;
}

__global__ void k_scan_add(unsigned* __restrict__ rowptr, const unsigned* __restrict__ blockoff) {
    int i = blockIdx.x * blockDim.x + threadIdx.x;
    if (i < N_NODES) rowptr[i] += blockoff[i >> 10];
    if (i == 0) rowptr[N_NODES] = N_EDGES;
}

// ---------------- bucket: esrc sorted by destination (int2-paired) ----------------

__global__ void k_bucket(const int* __restrict__ row, const int* __restrict__ col,
                         const unsigned* __restrict__ rowptr, unsigned* __restrict__ fill,
                         int* __restrict__ esrc) {
    int i = blockIdx.x * blockDim.x + threadIdx.x;
    int e = i * 2;
    if (e + 1 < N_EDGES) {
        int2 rr = *(const int2*)&row[e];
        int2 cc = *(const int2*)&col[e];
        unsigned p0 = rowptr[cc.x] + atomicAdd(&fill[cc.x], 1u);
        esrc[p0] = rr.x;
        unsigned p1 = rowptr[cc.y] + atomicAdd(&fill[cc.y], 1u);
        esrc[p1] = rr.y;
    } else if (e < N_EDGES) {
        int c = col[e];
        unsigned p = rowptr[c] + atomicAdd(&fill[c], 1u);
        esrc[p] = row[e];
    }
}

// ---------------- GEMM1 (MFMA bf16): hs[m][n] = dinv[m]*sum_k xbf[m][k]*W1t[n][k] ----------------

__global__ __launch_bounds__(256) void k_gemm1(const float* __restrict__ x,
                                               const ushort* __restrict__ W1t,
                                               const float* __restrict__ dinv,
                                               unsigned* __restrict__ hsu) {
    const int t = threadIdx.x;
    const int w = (blockIdx.x << 2) + (t >> 6);
    const int m0 = w << 4;
    if (m0 >= N_NODES) return;
    const int lane = t & 63;
    const int mrow = lane & 15;
    const int quad = lane >> 4;

    const float* xrow = x + (size_t)(m0 + mrow) * IN_DIM + quad * 8;
    const ushort* wrow = W1t + mrow * IN_DIM + quad * 8;

    f32x4 acc[8] = {};
#pragma unroll
    for (int ks = 0; ks < 8; ++ks) {
        float4 xa = *(const float4*)(xrow + ks * 32);
        float4 xb = *(const float4*)(xrow + ks * 32 + 4);
        bf16x8 bfrag;
        bfrag[0] = (short)f2bf(xa.x); bfrag[1] = (short)f2bf(xa.y);
        bfrag[2] = (short)f2bf(xa.z); bfrag[3] = (short)f2bf(xa.w);
        bfrag[4] = (short)f2bf(xb.x); bfrag[5] = (short)f2bf(xb.y);
        bfrag[6] = (short)f2bf(xb.z); bfrag[7] = (short)f2bf(xb.w);
        const ushort* wk = wrow + ks * 32;
#pragma unroll
        for (int nb = 0; nb < 8; ++nb) {
            bf16x8 afrag = *(const bf16x8*)(wk + nb * 16 * IN_DIM);
            acc[nb] = __builtin_amdgcn_mfma_f32_16x16x32_bf16(afrag, bfrag, acc[nb], 0, 0, 0);
        }
    }
    const float d = dinv[m0 + mrow];
    unsigned* orow = hsu + (size_t)(m0 + mrow) * 64;
#pragma unroll
    for (int nb = 0; nb < 8; ++nb) {
        unsigned p0 = (unsigned)f2bf(acc[nb][0] * d) | ((unsigned)f2bf(acc[nb][1] * d) << 16);
        unsigned p1 = (unsigned)f2bf(acc[nb][2] * d) | ((unsigned)f2bf(acc[nb][3] * d) << 16);
        *(uint2*)(orow + nb * 8 + quad * 2) = make_uint2(p0, p1);
    }
}

// ---------------- agg1 (CSR gather) + BN stats; S1 bf16; dual accumulators ----------------

__global__ __launch_bounds__(256) void k_agg1csr(const int* __restrict__ esrc,
                                                 const unsigned* __restrict__ rowptr,
                                                 const unsigned* __restrict__ hsu,
                                                 const float* __restrict__ dinv,
                                                 const float* __restrict__ b1,
                                                 unsigned* __restrict__ S1u,
                                                 float* __restrict__ stats) {
    const int t = threadIdx.x;
    const int lane = t & 63;
    const int gw = (blockIdx.x * blockDim.x + t) >> 6;
    const int nw = (gridDim.x * blockDim.x) >> 6;
    const int ch = lane * 2;
    const float2 bb = *(const float2*)&b1[ch];
    float s0 = 0.f, s1 = 0.f, q0 = 0.f, q1 = 0.f;

    for (int c = gw; c < N_NODES; c += nw) {
        const unsigned beg = rowptr[c], end = rowptr[c + 1];
        unsigned self = hsu[(size_t)c * 64 + lane];
        float a0 = bflo(self), a1 = bfhi(self);
        float e0 = 0.f, e1 = 0.f;                  // second accumulator pair (ILP)
        unsigned i = beg;
        for (; i + 8 <= end; i += 8) {
#pragma unroll
            for (int u = 0; u < 8; ++u) {
                int r = esrc[i + u];
                unsigned v = hsu[(size_t)r * 64 + lane];
                if (u & 1) { e0 += bflo(v); e1 += bfhi(v); }
                else       { a0 += bflo(v); a1 += bfhi(v); }
            }
        }
        for (; i < end; ++i) {
            int r = esrc[i];
            unsigned v = hsu[(size_t)r * 64 + lane];
            a0 += bflo(v); a1 += bfhi(v);
        }
        a0 += e0; a1 += e1;
        float d = dinv[c];
        float v0 = d * a0 + bb.x;
        float v1 = d * a1 + bb.y;
        S1u[(size_t)c * 64 + lane] = (unsigned)f2bf(v0) | ((unsigned)f2bf(v1) << 16);
        s0 += v0; s1 += v1; q0 += v0 * v0; q1 += v1 * v1;
    }

    __shared__ float red[256];
#define RED_ATOMIC(val, idx)                                              \
    red[t] = (val); __syncthreads();                                      \
    if (t < 64) {                                                         \
        float r_ = red[t] + red[t + 64] + red[t + 128] + red[t + 192];    \
        atomicAdd(&stats[idx], r_);                                       \
    } __syncthreads();
    RED_ATOMIC(s0, ch)
    RED_ATOMIC(s1, ch + 1)
    RED_ATOMIC(q0, 128 + ch)
    RED_ATOMIC(q1, 129 + ch)
#undef RED_ATOMIC
}

// ---------------- GEMM2 (BN finalize fused): gs[n] = dinv[n] * relu(bn(S1[n])) @ W2 ----------------

__global__ __launch_bounds__(256) void k_gemm2(const unsigned* __restrict__ S1u,
                                               const float* __restrict__ stats,
                                               const float* __restrict__ gamma,
                                               const float* __restrict__ beta,
                                               const float* __restrict__ W2,
                                               const float* __restrict__ dinv,
                                               float* __restrict__ gs) {
    int wid = (blockIdx.x * blockDim.x + threadIdx.x) >> 6;
    int lane = threadIdx.x & 63;
    int nw = (gridDim.x * blockDim.x) >> 6;
    int k0 = lane * 2;
    const float inv = 1.0f / (float)N_NODES;
    float mu0 = stats[k0] * inv, mu1 = stats[k0 + 1] * inv;
    float va0 = stats[128 + k0] * inv - mu0 * mu0;
    float va1 = stats[129 + k0] * inv - mu1 * mu1;
    float sc0 = rsqrtf(va0 + BN_EPS) * gamma[k0];
    float sc1 = rsqrtf(va1 + BN_EPS) * gamma[k0 + 1];
    float sh0 = beta[k0] - mu0 * sc0;
    float sh1 = beta[k0 + 1] - mu1 * sc1;
    float4 w = *(const float4*)&W2[k0 * 2];
    for (int n = wid; n < N_NODES; n += nw) {
        unsigned hv = S1u[(size_t)n * 64 + lane];
        float v0 = fmaxf(bflo(hv) * sc0 + sh0, 0.f);
        float v1 = fmaxf(bfhi(hv) * sc1 + sh1, 0.f);
        float a0 = v0 * w.x + v1 * w.z;
        float a1 = v0 * w.y + v1 * w.w;
#pragma unroll
        for (int off = 32; off; off >>= 1) {
            a0 += __shfl_down(a0, off);
            a1 += __shfl_down(a1, off);
        }
        if (lane == 0) {
            float d = dinv[n];
            *(float2*)&gs[n * 2] = make_float2(a0 * d, a1 * d);
        }
    }
}

// ---------------- agg2 (CSR gather, thread per node) + self-loop + dinv + b2 ----------------

__global__ __launch_bounds__(256) void k_agg2csr(const int* __restrict__ esrc,
                                                 const unsigned* __restrict__ rowptr,
                                                 const float* __restrict__ gs,
                                                 const float* __restrict__ dinv,
                                                 const float* __restrict__ b2,
                                                 float* __restrict__ out) {
    int c = blockIdx.x * blockDim.x + threadIdx.x;
    if (c >= N_NODES) return;
    float2 acc = *(const float2*)&gs[c * 2];
    float2 acc2 = make_float2(0.f, 0.f);
    unsigned beg = rowptr[c], end = rowptr[c + 1];
    unsigned i = beg;
    for (; i + 8 <= end; i += 8) {
#pragma unroll
        for (int u = 0; u < 8; ++u) {
            int r = esrc[i + u];
            float2 v = *(const float2*)&gs[r * 2];
            if (u & 1) { acc2.x += v.x; acc2.y += v.y; }
            else       { acc.x += v.x; acc.y += v.y; }
        }
    }
    for (; i < end; ++i) {
        int r = esrc[i];
        float2 v = *(const float2*)&gs[r * 2];
        acc.x += v.x; acc.y += v.y;
    }
    acc.x += acc2.x; acc.y += acc2.y;
    float d = dinv[c];
    *(float2*)&out[c * 2] = make_float2(d * acc.x + b2[0], d * acc.y + b2[1]);
}

// ---------------- launch ----------------

extern "C" void kernel_launch(void* const* d_in, const int* in_sizes, int n_in,
                              void* d_out, int out_size, void* d_ws, size_t ws_size,
                              hipStream_t stream) {
    const float* x     = (const float*)d_in[0];
    const int*   edge  = (const int*)d_in[1];      // [2, E]: row = edge[0..E), col = edge[E..2E)
    const float* fi    = (const float*)d_in[2];
    const float* W1    = (const float*)d_in[3];
    const float* b1    = (const float*)d_in[4];
    const float* W2    = (const float*)d_in[5];
    const float* b2    = (const float*)d_in[6];
    const float* gamma = (const float*)d_in[7];
    const float* beta  = (const float*)d_in[8];
    float* out = (float*)d_out;

    const int* erow = edge;
    const int* ecol = edge + N_EDGES;

    char* ws = (char*)d_ws;
    size_t off = 0;
    auto alloc = [&](size_t bytes) { size_t r = off; off = (off + bytes + 255) & ~(size_t)255; return r; };
    unsigned* hsu   = (unsigned*)(ws + alloc(sizeof(unsigned) * (size_t)N_NODES * 64)); // 25.6 MB
    unsigned* S1u   = (unsigned*)(ws + alloc(sizeof(unsigned) * (size_t)N_NODES * 64)); // 25.6 MB
    int*      esrc  = (int*)(ws + alloc(sizeof(int) * (size_t)N_EDGES));                // 12.8 MB
    float*    gs    = (float*)(ws + alloc(sizeof(float) * N_NODES * 2));                // 0.8 MB
    unsigned* cnt   = (unsigned*)(ws + alloc(sizeof(unsigned) * N_NODES * 2));          // cnt+fill adjacent
    unsigned* fill  = cnt + N_NODES;
    unsigned* rowptr= (unsigned*)(ws + alloc(sizeof(unsigned) * (N_NODES + 1)));
    unsigned* bsum  = (unsigned*)(ws + alloc(sizeof(unsigned) * NB1));
    unsigned* boff  = (unsigned*)(ws + alloc(sizeof(unsigned) * NB1));
    float*    dinv  = (float*)(ws + alloc(sizeof(float) * N_NODES));
    ushort*   W1t   = (ushort*)(ws + alloc(sizeof(ushort) * HID * IN_DIM));             // 64 KB
    float*    stats = (float*)(ws + alloc(sizeof(float) * 2 * HID));
    (void)ws_size; (void)in_sizes; (void)n_in; (void)out_size;

    hipMemsetAsync(cnt, 0, sizeof(unsigned) * N_NODES * 2, stream);
    hipMemsetAsync(stats, 0, sizeof(float) * 2 * HID, stream);

    k_deg<<<(N_EDGES / 2 + 255) / 256, 256, 0, stream>>>(ecol, cnt);
    k_prepw<<<(HID * IN_DIM + 255) / 256, 256, 0, stream>>>(W1, fi, W1t);

    k_scan_part<<<NB1, SCAN_B, 0, stream>>>(cnt, rowptr, bsum, dinv);
    k_scan_mid<<<1, 128, 0, stream>>>(bsum, boff);
    k_scan_add<<<(N_NODES + 255) / 256, 256, 0, stream>>>(rowptr, boff);
    k_bucket<<<(N_EDGES / 2 + 255) / 256, 256, 0, stream>>>(erow, ecol, rowptr, fill, esrc);

    k_gemm1<<<(N_NODES / 16 + 3) / 4, 256, 0, stream>>>(x, W1t, dinv, hsu);
    k_agg1csr<<<2048, 256, 0, stream>>>(esrc, rowptr, hsu, dinv, b1, S1u, stats);
    k_gemm2<<<2048, 256, 0, stream>>>(S1u, stats, gamma, beta, W2, dinv, gs);
    k_agg2csr<<<(N_NODES + 255) / 256, 256, 0, stream>>>(esrc, rowptr, gs, dinv, b2, out);
}